// Round 4
// baseline (20.145 us; speedup 1.0000x reference)
//
#include <hip/hip_runtime.h>
#include <hip/hip_bf16.h>

// ---------------------------------------------------------------------------
// HybridQuantumNet: 4-qubit default.qubit sim + Linear(2,2), B = 524288.
//
// out[b][o] = sum_{k in 3^4} C[k][o] * prod_q g_{k_q}(x_q), g = (1, cos, sin).
// C (162 floats, weights/fc-only) is computed per-block (redundantly) into a
// private d_ws slice, then contracted per element: 4 sincos + ~170 FMA.
// Single fused kernel: 512 blocks x 256 threads x 4 elements/thread,
// one element at a time (a2[54] single buffer, ~100 VGPR, no spill risk).
// ---------------------------------------------------------------------------

#define NBLK 512
#define NTHR 256
#define EPT  4                       // elements per thread
#define CSLICE 256                   // floats per block slice in ws (1 KB)

__global__ __launch_bounds__(256) void qfused_kernel(
    const float4* __restrict__ x,    // [B] angle quads
    const float*  __restrict__ w,    // [2][4][3]
    const float*  __restrict__ fcw,  // [2][2]
    const float*  __restrict__ fcb,  // [2]
    float*        __restrict__ ws,   // >= NBLK*CSLICE floats
    float2*       __restrict__ out,  // [B]
    int B)
{
    __shared__ float rot[8][8];
    __shared__ float Ur[16][16], Ui[16][16];
    __shared__ float Mr[2][16][16], Mi[2][16][16];

    const int t = threadIdx.x;
    const int stride = NBLK * NTHR;
    const int base = blockIdx.x * NTHR + t;
    float* Cg = ws + (size_t)blockIdx.x * CSLICE;

    // Issue the streaming x-loads up front; latency hides under prep.
    float4 xv[EPT];
#pragma unroll
    for (int e = 0; e < EPT; ++e) {
        int el = base + e * stride;
        if (el < B) xv[e] = x[el];
    }

    // ===================== per-block prep: weights -> C ====================
    // 1: Rot matrices. Rot = RZ(om) RY(th) RZ(phi).
    if (t < 8) {
        float phi = w[t*3+0], th = w[t*3+1], om = w[t*3+2];
        float ct = cosf(0.5f*th), st = sinf(0.5f*th);
        float sp, cp, sm, cm;
        sincosf(0.5f*(phi+om), &sp, &cp);
        sincosf(0.5f*(phi-om), &sm, &cm);
        rot[t][0] =  cp*ct;  rot[t][1] = -sp*ct;
        rot[t][2] = -cm*st;  rot[t][3] = -sm*st;
        rot[t][4] =  cm*st;  rot[t][5] = -sm*st;
        rot[t][6] =  cp*ct;  rot[t][7] =  sp*ct;
    }
    __syncthreads();

    // 2: build U columns (wire q <-> bit (3-q))
    if (t < 16) {
        float re[16], im[16];
#pragma unroll
        for (int i = 0; i < 16; ++i) { re[i] = 0.0f; im[i] = 0.0f; }
        re[t] = 1.0f;
#pragma unroll
        for (int l = 0; l < 2; ++l) {
#pragma unroll
            for (int q = 0; q < 4; ++q) {
                const float* m = rot[l*4 + q];
                float m00r=m[0],m00i=m[1],m01r=m[2],m01i=m[3];
                float m10r=m[4],m10i=m[5],m11r=m[6],m11i=m[7];
                const int bit = 8 >> q;
#pragma unroll
                for (int i = 0; i < 16; ++i) {
                    if (i & bit) continue;
                    const int j = i | bit;
                    float a0r=re[i], a0i=im[i], a1r=re[j], a1i=im[j];
                    re[i] = m00r*a0r - m00i*a0i + m01r*a1r - m01i*a1i;
                    im[i] = m00r*a0i + m00i*a0r + m01r*a1i + m01i*a1r;
                    re[j] = m10r*a0r - m10i*a0i + m11r*a1r - m11i*a1i;
                    im[j] = m10r*a0i + m10i*a0r + m11r*a1i + m11i*a1r;
                }
            }
            const int r = (l % 3) + 1;
#pragma unroll
            for (int q = 0; q < 4; ++q) {
                const int cbit = 8 >> q;
                const int tbit = 8 >> ((q + r) & 3);
#pragma unroll
                for (int i = 0; i < 16; ++i) {
                    if ((i & cbit) && !(i & tbit)) {
                        const int j = i | tbit;
                        float tr = re[i]; re[i] = re[j]; re[j] = tr;
                        float ti = im[i]; im[i] = im[j]; im[j] = ti;
                    }
                }
            }
        }
#pragma unroll
        for (int k = 0; k < 16; ++k) { Ur[k][t] = re[k]; Ui[k][t] = im[k]; }
    }
    __syncthreads();

    // 3: M_o = U^dag Z_o U  (o=0: sign bit8, o=1: sign bit4)
    {
        const int i = t >> 4, j = t & 15;
        float r0=0, i0=0, r1=0, i1=0;
#pragma unroll
        for (int k = 0; k < 16; ++k) {
            float ar = Ur[k][i], ai = Ui[k][i];
            float br = Ur[k][j], bi = Ui[k][j];
            float pr = ar*br + ai*bi;
            float pi = ar*bi - ai*br;
            float sg0 = (k & 8) ? -1.0f : 1.0f;
            float sg1 = (k & 4) ? -1.0f : 1.0f;
            r0 += sg0*pr; i0 += sg0*pi;
            r1 += sg1*pr; i1 += sg1*pi;
        }
        Mr[0][i][j] = r0; Mi[0][i][j] = i0;
        Mr[1][i][j] = r1; Mi[1][i][j] = i1;
    }
    __syncthreads();

    // 4: project onto per-qubit {1, cos, sin} basis, fold fc, write Cg.
    // Layout: Cg[k0*64 + (k1*9+k2*3+k3)*2 + o]  (3 segments of 54, 256B apart)
    if (t < 81) {
        const int k3 = t % 3, k2 = (t/3) % 3, k1 = (t/9) % 3, k0 = t / 27;
        const int kd[4] = {k0, k1, k2, k3};
        int mask2 = 0, mask1 = 0;
#pragma unroll
        for (int q = 0; q < 4; ++q) {
            const int bit = 8 >> q;
            if (kd[q] == 2) mask2 |= bit;
            else if (kd[q] == 1) mask1 |= bit;
        }
        float z[2];
#pragma unroll
        for (int o = 0; o < 2; ++o) {
            float cr = 0.0f;
            for (int i = 0; i < 16; ++i) {
                const int j = i ^ mask2;
                const float mr = Mr[o][i][j], mi = Mi[o][i][j];
                const int s1 = __popc(mask1 & i) & 1;
                const int a  = __popc(mask2 & i);
                const int bb = __popc(mask2) - a;
                const int ip = ((a - bb) % 4 + 4) & 3;
                float wr, wi;
                switch (ip) {
                    case 0:  wr =  1.0f; wi =  0.0f; break;
                    case 1:  wr =  0.0f; wi =  1.0f; break;
                    case 2:  wr = -1.0f; wi =  0.0f; break;
                    default: wr =  0.0f; wi = -1.0f; break;
                }
                if (s1) { wr = -wr; wi = -wi; }
                cr += wr*mr - wi*mi;
            }
            z[o] = cr * 0.0625f;
        }
        const int rest = (t % 27) * 2;
#pragma unroll
        for (int o = 0; o < 2; ++o) {
            float v = z[0]*fcw[o*2+0] + z[1]*fcw[o*2+1];
            if (t == 0) v += fcb[o];
            Cg[k0*64 + rest + o] = v;
        }
    }
    __syncthreads();

    // ===================== main: one element at a time =====================
#pragma unroll
    for (int e = 0; e < EPT; ++e) {
        float cc[4], ss[4];
        __sincosf(xv[e].x, &ss[0], &cc[0]);
        __sincosf(xv[e].y, &ss[1], &cc[1]);
        __sincosf(xv[e].z, &ss[2], &cc[2]);
        __sincosf(xv[e].w, &ss[3], &cc[3]);

        float a2[54];
#pragma unroll
        for (int mq = 0; mq < 14; ++mq) {
            const float4 q0 = *(const float4*)(Cg +       mq*4);
            const float4 q1 = *(const float4*)(Cg +  64 + mq*4);
            const float4 q2 = *(const float4*)(Cg + 128 + mq*4);
            const int m = mq * 4;
            if (m + 0 < 54) a2[m+0] = fmaf(ss[0], q2.x, fmaf(cc[0], q1.x, q0.x));
            if (m + 1 < 54) a2[m+1] = fmaf(ss[0], q2.y, fmaf(cc[0], q1.y, q0.y));
            if (m + 2 < 54) a2[m+2] = fmaf(ss[0], q2.z, fmaf(cc[0], q1.z, q0.z));
            if (m + 3 < 54) a2[m+3] = fmaf(ss[0], q2.w, fmaf(cc[0], q1.w, q0.w));
        }

        float a3[18];
#pragma unroll
        for (int n = 0; n < 18; ++n)
            a3[n] = fmaf(ss[1], a2[36+n], fmaf(cc[1], a2[18+n], a2[n]));

        float a4[6];
#pragma unroll
        for (int p = 0; p < 6; ++p)
            a4[p] = fmaf(ss[2], a3[12+p], fmaf(cc[2], a3[6+p], a3[p]));

        float2 o;
        o.x = fmaf(ss[3], a4[4], fmaf(cc[3], a4[2], a4[0]));
        o.y = fmaf(ss[3], a4[5], fmaf(cc[3], a4[3], a4[1]));

        const int el = base + e * stride;
        if (el < B) out[el] = o;
    }
}

extern "C" void kernel_launch(void* const* d_in, const int* in_sizes, int n_in,
                              void* d_out, int out_size, void* d_ws, size_t ws_size,
                              hipStream_t stream) {
    const float* x   = (const float*)d_in[0];   // [B,4]
    const float* w   = (const float*)d_in[1];   // [2,4,3]
    const float* fcw = (const float*)d_in[2];   // [2,2]
    const float* fcb = (const float*)d_in[3];   // [2]
    float* out = (float*)d_out;                 // [B,2]
    float* ws  = (float*)d_ws;

    const int B = in_sizes[0] / 4;

    qfused_kernel<<<NBLK, NTHR, 0, stream>>>(
        (const float4*)x, w, fcw, fcb, ws, (float2*)out, B);
}

// Round 5
// 17.192 us; speedup vs baseline: 1.1717x; 1.1717x over previous
//
#include <hip/hip_runtime.h>
#include <hip/hip_bf16.h>

// ---------------------------------------------------------------------------
// HybridQuantumNet: 4-qubit default.qubit sim + Linear(2,2), B = 524288.
//
// out[b][o] = sum_{k in 3^4} C[k][o] * prod_q g_{k_q}(x_q), g = (1, cos, sin).
// C (162 floats, weights/fc-only) is computed per-block (redundantly) into
// LDS, then contracted per element: 4 sincos + ~160 FMA, two elements
// interleaved for ILP. 512 blocks x 256 threads x 4 elements/thread.
// ---------------------------------------------------------------------------

#define NBLK 512
#define NTHR 256
#define EPT  4                       // elements per thread

__global__ __launch_bounds__(256) void qfused_kernel(
    const float4* __restrict__ x,    // [B] angle quads
    const float*  __restrict__ w,    // [2][4][3]
    const float*  __restrict__ fcw,  // [2][2]
    const float*  __restrict__ fcb,  // [2]
    float2*       __restrict__ out,  // [B]
    int B)
{
    __shared__ float rot[8][8];
    __shared__ float Ur[16][16], Ui[16][16];
    __shared__ float Mr[2][16][16], Mi[2][16][16];
    __shared__ alignas(16) float Cs[192];   // 3 segments of 54, 64-float apart

    const int t = threadIdx.x;
    const int stride = NBLK * NTHR;
    const int base = blockIdx.x * NTHR + t;

    // Issue the streaming x-loads up front; latency hides under prep.
    float4 xv[EPT];
#pragma unroll
    for (int e = 0; e < EPT; ++e) {
        int el = base + e * stride;
        if (el < B) xv[e] = x[el];
    }

    // ===================== per-block prep: weights -> Cs ===================
    // 1: Rot matrices. Rot = RZ(om) RY(th) RZ(phi).
    if (t < 8) {
        float phi = w[t*3+0], th = w[t*3+1], om = w[t*3+2];
        float ct = cosf(0.5f*th), st = sinf(0.5f*th);
        float sp, cp, sm, cm;
        sincosf(0.5f*(phi+om), &sp, &cp);
        sincosf(0.5f*(phi-om), &sm, &cm);
        rot[t][0] =  cp*ct;  rot[t][1] = -sp*ct;
        rot[t][2] = -cm*st;  rot[t][3] = -sm*st;
        rot[t][4] =  cm*st;  rot[t][5] = -sm*st;
        rot[t][6] =  cp*ct;  rot[t][7] =  sp*ct;
    }
    __syncthreads();

    // 2: build U columns (wire q <-> bit (3-q))
    if (t < 16) {
        float re[16], im[16];
#pragma unroll
        for (int i = 0; i < 16; ++i) { re[i] = 0.0f; im[i] = 0.0f; }
        re[t] = 1.0f;
#pragma unroll
        for (int l = 0; l < 2; ++l) {
#pragma unroll
            for (int q = 0; q < 4; ++q) {
                const float* m = rot[l*4 + q];
                float m00r=m[0],m00i=m[1],m01r=m[2],m01i=m[3];
                float m10r=m[4],m10i=m[5],m11r=m[6],m11i=m[7];
                const int bit = 8 >> q;
#pragma unroll
                for (int i = 0; i < 16; ++i) {
                    if (i & bit) continue;
                    const int j = i | bit;
                    float a0r=re[i], a0i=im[i], a1r=re[j], a1i=im[j];
                    re[i] = m00r*a0r - m00i*a0i + m01r*a1r - m01i*a1i;
                    im[i] = m00r*a0i + m00i*a0r + m01r*a1i + m01i*a1r;
                    re[j] = m10r*a0r - m10i*a0i + m11r*a1r - m11i*a1i;
                    im[j] = m10r*a0i + m10i*a0r + m11r*a1i + m11i*a1r;
                }
            }
            const int r = (l % 3) + 1;
#pragma unroll
            for (int q = 0; q < 4; ++q) {
                const int cbit = 8 >> q;
                const int tbit = 8 >> ((q + r) & 3);
#pragma unroll
                for (int i = 0; i < 16; ++i) {
                    if ((i & cbit) && !(i & tbit)) {
                        const int j = i | tbit;
                        float tr = re[i]; re[i] = re[j]; re[j] = tr;
                        float ti = im[i]; im[i] = im[j]; im[j] = ti;
                    }
                }
            }
        }
#pragma unroll
        for (int k = 0; k < 16; ++k) { Ur[k][t] = re[k]; Ui[k][t] = im[k]; }
    }
    __syncthreads();

    // 3: M_o = U^dag Z_o U  (o=0: sign bit8, o=1: sign bit4)
    {
        const int i = t >> 4, j = t & 15;
        float r0=0, i0=0, r1=0, i1=0;
#pragma unroll
        for (int k = 0; k < 16; ++k) {
            float ar = Ur[k][i], ai = Ui[k][i];
            float br = Ur[k][j], bi = Ui[k][j];
            float pr = ar*br + ai*bi;
            float pi = ar*bi - ai*br;
            float sg0 = (k & 8) ? -1.0f : 1.0f;
            float sg1 = (k & 4) ? -1.0f : 1.0f;
            r0 += sg0*pr; i0 += sg0*pi;
            r1 += sg1*pr; i1 += sg1*pi;
        }
        Mr[0][i][j] = r0; Mi[0][i][j] = i0;
        Mr[1][i][j] = r1; Mi[1][i][j] = i1;
    }
    __syncthreads();

    // 4: project onto per-qubit {1, cos, sin} basis, fold fc, write Cs.
    // Layout: Cs[k0*64 + (k1*9+k2*3+k3)*2 + o]
    if (t < 81) {
        const int k3 = t % 3, k2 = (t/3) % 3, k1 = (t/9) % 3, k0 = t / 27;
        const int kd[4] = {k0, k1, k2, k3};
        int mask2 = 0, mask1 = 0;
#pragma unroll
        for (int q = 0; q < 4; ++q) {
            const int bit = 8 >> q;
            if (kd[q] == 2) mask2 |= bit;
            else if (kd[q] == 1) mask1 |= bit;
        }
        float z[2];
#pragma unroll
        for (int o = 0; o < 2; ++o) {
            float cr = 0.0f;
            for (int i = 0; i < 16; ++i) {
                const int j = i ^ mask2;
                const float mr = Mr[o][i][j], mi = Mi[o][i][j];
                const int s1 = __popc(mask1 & i) & 1;
                const int a  = __popc(mask2 & i);
                const int bb = __popc(mask2) - a;
                const int ip = ((a - bb) % 4 + 4) & 3;
                float wr, wi;
                switch (ip) {
                    case 0:  wr =  1.0f; wi =  0.0f; break;
                    case 1:  wr =  0.0f; wi =  1.0f; break;
                    case 2:  wr = -1.0f; wi =  0.0f; break;
                    default: wr =  0.0f; wi = -1.0f; break;
                }
                if (s1) { wr = -wr; wi = -wi; }
                cr += wr*mr - wi*mi;
            }
            z[o] = cr * 0.0625f;
        }
        const int rest = (t % 27) * 2;
#pragma unroll
        for (int o = 0; o < 2; ++o) {
            float v = z[0]*fcw[o*2+0] + z[1]*fcw[o*2+1];
            if (t == 0) v += fcb[o];
            Cs[k0*64 + rest + o] = v;
        }
    }
    __syncthreads();

    // ===================== main: 2 pairs of elements ======================
#pragma unroll
    for (int pp = 0; pp < EPT / 2; ++pp) {
        const int eA = 2*pp, eB = 2*pp + 1;
        float cA[4], sA[4], cB[4], sB[4];
        __sincosf(xv[eA].x, &sA[0], &cA[0]);
        __sincosf(xv[eA].y, &sA[1], &cA[1]);
        __sincosf(xv[eA].z, &sA[2], &cA[2]);
        __sincosf(xv[eA].w, &sA[3], &cA[3]);
        __sincosf(xv[eB].x, &sB[0], &cB[0]);
        __sincosf(xv[eB].y, &sB[1], &cB[1]);
        __sincosf(xv[eB].z, &sB[2], &cB[2]);
        __sincosf(xv[eB].w, &sB[3], &cB[3]);

        float a2A[54], a2B[54];
#define S1(mm, v0, v1, v2)                                      \
        if ((mm) < 54) {                                        \
            a2A[mm] = fmaf(sA[0], v2, fmaf(cA[0], v1, v0));     \
            a2B[mm] = fmaf(sB[0], v2, fmaf(cB[0], v1, v0));     \
        }
#pragma unroll
        for (int mq = 0; mq < 14; ++mq) {
            const float4 q0 = *(const float4*)(Cs +       mq*4);
            const float4 q1 = *(const float4*)(Cs +  64 + mq*4);
            const float4 q2 = *(const float4*)(Cs + 128 + mq*4);
            S1(mq*4+0, q0.x, q1.x, q2.x);
            S1(mq*4+1, q0.y, q1.y, q2.y);
            S1(mq*4+2, q0.z, q1.z, q2.z);
            S1(mq*4+3, q0.w, q1.w, q2.w);
        }
#undef S1

#pragma unroll
        for (int half = 0; half < 2; ++half) {
            const float* a2 = half ? a2B : a2A;
            const float* cc = half ? cB : cA;
            const float* ss = half ? sB : sA;
            float a3[18];
#pragma unroll
            for (int n = 0; n < 18; ++n)
                a3[n] = fmaf(ss[1], a2[36+n], fmaf(cc[1], a2[18+n], a2[n]));
            float a4[6];
#pragma unroll
            for (int p = 0; p < 6; ++p)
                a4[p] = fmaf(ss[2], a3[12+p], fmaf(cc[2], a3[6+p], a3[p]));
            float2 o;
            o.x = fmaf(ss[3], a4[4], fmaf(cc[3], a4[2], a4[0]));
            o.y = fmaf(ss[3], a4[5], fmaf(cc[3], a4[3], a4[1]));
            const int el = base + (2*pp + half) * stride;
            if (el < B) out[el] = o;
        }
    }
}

extern "C" void kernel_launch(void* const* d_in, const int* in_sizes, int n_in,
                              void* d_out, int out_size, void* d_ws, size_t ws_size,
                              hipStream_t stream) {
    const float* x   = (const float*)d_in[0];   // [B,4]
    const float* w   = (const float*)d_in[1];   // [2,4,3]
    const float* fcw = (const float*)d_in[2];   // [2,2]
    const float* fcb = (const float*)d_in[3];   // [2]
    float* out = (float*)d_out;                 // [B,2]

    const int B = in_sizes[0] / 4;

    qfused_kernel<<<NBLK, NTHR, 0, stream>>>(
        (const float4*)x, w, fcw, fcb, (float2*)out, B);
}